// Round 14
// baseline (90.398 us; speedup 1.0000x reference)
//
#include <hip/hip_runtime.h>
#include <math.h>

#define BIG_NEG -1.0e9f

typedef float f4 __attribute__((ext_vector_type(4)));

// Problem constants (fixed by setup_inputs)
constexpr int B  = 4;
constexpr int N1 = 511;
constexpr int C1 = 31;
constexpr int K  = 32;
constexpr int N  = N1 + 1;        // 512
constexpr int C  = C1 + 1;        // 32

// Workspace layout (float offsets)
constexpr int WS_TRANS = 0;                    // [32][32]
constexpr int WS_INIT  = 1024;                 // [32]
constexpr int WS_LEN   = 1056;                 // [32][32]  (K x C)
constexpr int WS_P     = 2080;                 // [64][64]  precision matrix
constexpr int WS_W     = 6176;                 // [64][32]  wT[dd][c]
constexpr int WS_BIAS  = 8224;                 // [32]

// ---------------------------------------------------------------------------
// Fused prep: rank-4 frozen-pivot-row block Gauss-Jordan (16 barriers).
// [verified R9/R12 — unchanged]
// ---------------------------------------------------------------------------
__global__ __launch_bounds__(512) void k_prep(const float* __restrict__ tl,
                                              const float* __restrict__ il,
                                              const float* __restrict__ plr,
                                              const float* __restrict__ cov,
                                              const float* __restrict__ means,
                                              float* __restrict__ ws) {
    __shared__ float M[64][132];    // [cov | I], row stride 132 (16B aligned)
    __shared__ float cP[2][4][64];  // published pivot cols s..s+3 (dbuf)
    __shared__ float Bsave[16][16]; // B_k blocks, row-major
    __shared__ float mu[C1][64];

    const int tid = threadIdx.x;
    const int ii = tid >> 3;       // row 0..63
    const int cg = tid & 7;        // owns f4 chunks {cg, cg+8, cg+16, cg+24}

    f4* Mrow = (f4*)&M[ii][0];

    // ---- small tables (disjoint writers, no race) ----
    for (int idx = tid; idx < 1024; idx += 512) {
        const int i = idx >> 5, j = idx & 31;
        float lv;
        if (j < C1) {
            float lr = plr[j];
            lv = (float)i * lr - expf(lr) - lgammaf((float)i + 1.0f);
        } else {
            lv = (i == 1) ? 0.0f : BIG_NEG;
        }
        ws[WS_LEN + idx] = lv;
        if (i == C1) ws[WS_TRANS + idx] = 0.0f;
        else if (j == C1) ws[WS_TRANS + idx] = BIG_NEG;
    }
    // trans columns: log_softmax over axis 0 with masked diagonal
    if (tid < C1) {
        const int jj = tid;
        float m = BIG_NEG;
        for (int r = 0; r < C1; ++r) {
            float v = (r == jj) ? BIG_NEG : tl[r * C1 + jj];
            m = fmaxf(m, v);
        }
        float s = 0.0f;
        for (int r = 0; r < C1; ++r) {
            float v = (r == jj) ? BIG_NEG : tl[r * C1 + jj];
            s += expf(v - m);
        }
        float lse = m + logf(s);
        for (int r = 0; r < C1; ++r) {
            float v = (r == jj) ? BIG_NEG : tl[r * C1 + jj];
            ws[WS_TRANS + r * 32 + jj] = v - lse;
        }
    }
    // init_a
    if (tid == 32) {
        float m = -1.0e30f;
        for (int cc = 0; cc < C1; ++cc) m = fmaxf(m, il[cc]);
        float s = 0.0f;
        for (int cc = 0; cc < C1; ++cc) s += expf(il[cc] - m);
        float lse = m + logf(s);
        for (int cc = 0; cc < C1; ++cc) ws[WS_INIT + cc] = il[cc] - lse;
        ws[WS_INIT + C1] = BIG_NEG;
    }

    // ---- load [cov | I] ----
    {
        Mrow[cg]     = *(const f4*)&cov[ii * 64 + 4 * cg];
        Mrow[cg + 8] = *(const f4*)&cov[ii * 64 + 4 * (cg + 8)];
        const int r0 = 4 * cg, r1 = 4 * (cg + 8);
        f4 e1 = {(ii == r0) ? 1.f : 0.f, (ii == r0 + 1) ? 1.f : 0.f,
                 (ii == r0 + 2) ? 1.f : 0.f, (ii == r0 + 3) ? 1.f : 0.f};
        f4 e2 = {(ii == r1) ? 1.f : 0.f, (ii == r1 + 1) ? 1.f : 0.f,
                 (ii == r1 + 2) ? 1.f : 0.f, (ii == r1 + 3) ? 1.f : 0.f};
        Mrow[cg + 16] = e1;
        Mrow[cg + 24] = e2;
    }
    if (cg == 0) {
        cP[0][0][ii] = cov[ii * 64 + 0];
        cP[0][1][ii] = cov[ii * 64 + 1];
        cP[0][2][ii] = cov[ii * 64 + 2];
        cP[0][3][ii] = cov[ii * 64 + 3];
    }
    for (int idx = tid; idx < C1 * 64; idx += 512)
        mu[idx >> 6][idx & 63] = means[idx];
    __syncthreads();

    // ---- rank-4 block GJ: 16 steps, ONE barrier each, pivot rows frozen ----
    float detprod = 1.0f;
    for (int st = 0; st < 16; ++st) {
        const int s = st << 2;
        const int par = st & 1;
        const float T00 = cP[par][0][s + 0], T01 = cP[par][0][s + 1],
                    T02 = cP[par][0][s + 2], T03 = cP[par][0][s + 3];
        const float T10 = cP[par][1][s + 0], T11 = cP[par][1][s + 1],
                    T12 = cP[par][1][s + 2], T13 = cP[par][1][s + 3];
        const float T20 = cP[par][2][s + 0], T21 = cP[par][2][s + 1],
                    T22 = cP[par][2][s + 2], T23 = cP[par][2][s + 3];
        const float T30 = cP[par][3][s + 0], T31 = cP[par][3][s + 1],
                    T32 = cP[par][3][s + 2], T33 = cP[par][3][s + 3];
        const float r0 = __builtin_amdgcn_rcpf(T00);
        const float l10 = T10 * r0, l20 = T20 * r0, l30 = T30 * r0;
        const float u11 = T11 - l10 * T01, u12 = T12 - l10 * T02,
                    u13 = T13 - l10 * T03;
        const float r1 = __builtin_amdgcn_rcpf(u11);
        const float l21 = (T21 - l20 * T01) * r1;
        const float l31 = (T31 - l30 * T01) * r1;
        const float u22 = T22 - l20 * T02 - l21 * u12;
        const float u23 = T23 - l20 * T03 - l21 * u13;
        const float u32 = T32 - l30 * T02 - l31 * u12;
        const float u33t = T33 - l30 * T03 - l31 * u13;
        const float r2 = __builtin_amdgcn_rcpf(u22);
        const float l32 = u32 * r2;
        const float u33 = u33t - l32 * u23;
        const float r3 = __builtin_amdgcn_rcpf(u33);
        detprod *= T00 * u11 * u22 * u33;

        if (tid < 16) Bsave[st][tid] = cP[par][tid & 3][s + (tid >> 2)];

        const float m0 = cP[par][0][ii], m1 = cP[par][1][ii],
                    m2 = cP[par][2][ii], m3 = cP[par][3][ii];
        const float y0 = m0;
        const float y1 = m1 - l10 * y0;
        const float y2 = m2 - l20 * y0 - l21 * y1;
        const float y3 = m3 - l30 * y0 - l31 * y1 - l32 * y2;
        float g3 = y3 * r3;
        float g2 = (y2 - u23 * g3) * r2;
        float g1 = (y1 - u12 * g2 - u13 * g3) * r1;
        float g0 = (y0 - T01 * g1 - T02 * g2 - T03 * g3) * r0;
        const bool pivrow = (unsigned)(ii - s) < 4u;
        if (pivrow) { g0 = 0.f; g1 = 0.f; g2 = 0.f; g3 = 0.f; }

        const f4* Ms0 = (const f4*)&M[s + 0][0];
        const f4* Ms1 = (const f4*)&M[s + 1][0];
        const f4* Ms2 = (const f4*)&M[s + 2][0];
        const f4* Ms3 = (const f4*)&M[s + 3][0];
        const int qpub = st + 1;   // chunk holding cols s+4..s+7
#pragma unroll
        for (int h = 0; h < 4; ++h) {
            const int q = cg + 8 * h;
            const int k0 = 4 * q;
            const bool active = (k0 < 64) ? (k0 + 3 >= s) : (k0 - 64 <= s + 3);
            if (!active) continue;
            f4 v = Mrow[q] - g0 * Ms0[q] - g1 * Ms1[q]
                           - g2 * Ms2[q] - g3 * Ms3[q];
            if (!pivrow) Mrow[q] = v;      // pivot rows frozen (no race)
            if (st < 15 && q == qpub) {
                cP[par ^ 1][0][ii] = v.x;
                cP[par ^ 1][1][ii] = v.y;
                cP[par ^ 1][2][ii] = v.z;
                cP[par ^ 1][3][ii] = v.w;
            }
        }
        __syncthreads();
    }

    // ---- extraction: P[ii][:] = (invB_k row (ii&3)) . Mright[4k..4k+3][:] ----
    {
        const int kb = ii >> 2, rsel = ii & 3, base = kb << 2;
        const float* Bk = &Bsave[kb][0];
        const float T00 = Bk[0],  T01 = Bk[4],  T02 = Bk[8],  T03 = Bk[12];
        const float T10 = Bk[1],  T11 = Bk[5],  T12 = Bk[9],  T13 = Bk[13];
        const float T20 = Bk[2],  T21 = Bk[6],  T22 = Bk[10], T23 = Bk[14];
        const float T30 = Bk[3],  T31 = Bk[7],  T32 = Bk[11], T33 = Bk[15];
        const float r0 = __builtin_amdgcn_rcpf(T00);
        const float l10 = T10 * r0, l20 = T20 * r0, l30 = T30 * r0;
        const float u11 = T11 - l10 * T01, u12 = T12 - l10 * T02,
                    u13 = T13 - l10 * T03;
        const float r1 = __builtin_amdgcn_rcpf(u11);
        const float l21 = (T21 - l20 * T01) * r1;
        const float l31 = (T31 - l30 * T01) * r1;
        const float u22 = T22 - l20 * T02 - l21 * u12;
        const float u23 = T23 - l20 * T03 - l21 * u13;
        const float u32 = T32 - l30 * T02 - l31 * u12;
        const float u33t = T33 - l30 * T03 - l31 * u13;
        const float r2 = __builtin_amdgcn_rcpf(u22);
        const float l32 = u32 * r2;
        const float u33 = u33t - l32 * u23;
        const float r3 = __builtin_amdgcn_rcpf(u33);
        const float m0 = (rsel == 0) ? 1.f : 0.f;
        const float m1 = (rsel == 1) ? 1.f : 0.f;
        const float m2 = (rsel == 2) ? 1.f : 0.f;
        const float m3 = (rsel == 3) ? 1.f : 0.f;
        const float y0 = m0;
        const float y1 = m1 - l10 * y0;
        const float y2 = m2 - l20 * y0 - l21 * y1;
        const float y3 = m3 - l30 * y0 - l31 * y1 - l32 * y2;
        const float x3 = y3 * r3;
        const float x2 = (y2 - u23 * x3) * r2;
        const float x1 = (y1 - u12 * x2 - u13 * x3) * r1;
        const float x0 = (y0 - T01 * x1 - T02 * x2 - T03 * x3) * r0;

        const f4* R0 = (const f4*)&M[base + 0][64];
        const f4* R1 = (const f4*)&M[base + 1][64];
        const f4* R2 = (const f4*)&M[base + 2][64];
        const f4* R3 = (const f4*)&M[base + 3][64];
        f4 va = x0 * R0[cg] + x1 * R1[cg] + x2 * R2[cg] + x3 * R3[cg];
        f4 vb = x0 * R0[cg + 8] + x1 * R1[cg + 8] +
                x2 * R2[cg + 8] + x3 * R3[cg + 8];
        *(f4*)&ws[WS_P + ii * 64 + 4 * cg] = va;
        *(f4*)&ws[WS_P + ii * 64 + 32 + 4 * cg] = vb;
        *(f4*)&M[ii][4 * cg] = va;          // stash P in left half for wT
        *(f4*)&M[ii][32 + 4 * cg] = vb;
    }
    __syncthreads();

    // ---- wT[dd][c] = P[dd][:] . mu_c ; bias via shfl ----
    {
        const int c = tid >> 4;    // 0..31
        const int l = tid & 15;
        if (c < C1) {
            const f4* muc = (const f4*)&mu[c][0];
            float qacc = 0.0f;
#pragma unroll
            for (int h = 0; h < 4; ++h) {
                const int dd = l + 16 * h;
                const f4* Mr = (const f4*)&M[dd][0];
                f4 a4 = {0.f, 0.f, 0.f, 0.f};
#pragma unroll
                for (int e4 = 0; e4 < 16; ++e4) a4 += Mr[e4] * muc[e4];
                float a = (a4.x + a4.y) + (a4.z + a4.w);
                ws[WS_W + dd * 32 + c] = a;
                qacc += a * mu[c][dd];
            }
            for (int m2 = 8; m2 >= 1; m2 >>= 1) qacc += __shfl_xor(qacc, m2, 64);
            if (l == 0)
                ws[WS_BIAS + c] = -0.5f * (64.0f * 1.8378770664093453f +
                                           logf(detprod) + qacc);
        }
    }
}

// ---------------------------------------------------------------------------
// Fused main: one block per (b, 2-t tile); grid = 1024 (~4 blocks/CU).
// Stage P/W/bias + 32 feat rows in LDS, compute the 32 needed emission rows
// in-block (R10-verified coalesced pattern: sP[dd][lane], broadcast sx),
// prefix-scan, then R12's verified coalesced plain-f4 store loop.
// ---------------------------------------------------------------------------
__global__ __launch_bounds__(256) void k_main(const float* __restrict__ feat,
                                              const float* __restrict__ ws,
                                              float* __restrict__ out) {
    constexpr int TT = 2;
    const int bid = blockIdx.x;
    const int b = bid >> 8;
    const int t0 = (bid & 255) << 1;
    const int tid = threadIdx.x;
    const int w = tid >> 6, lane = tid & 63;

    __shared__ float sP[64][64];   // 16 KB  precision matrix
    __shared__ float sW[64][32];   // 8 KB   wT[dd][c]
    __shared__ float sx[32][64];   // 8 KB   feat rows t0..t0+31
    __shared__ float sh[41][36];   // 5.9 KB S[0..40] per column
    __shared__ float sb[32];       // bias

    // ---- stage tables + feat rows ----
    {
        float* p = &sP[0][0];
        for (int i = tid; i < 1024; i += 256)
            *(f4*)&p[4 * i] = *(const f4*)&ws[WS_P + 4 * i];
        float* q = &sW[0][0];
        for (int i = tid; i < 512; i += 256)
            *(f4*)&q[4 * i] = *(const f4*)&ws[WS_W + 4 * i];
        if (tid < 32) { sb[tid] = ws[WS_BIAS + tid]; sh[0][tid] = 0.f; }
        // zero scan rows 33..40 (8 rows x 32)
        if (tid >= 64 && tid < 64 + 256 - 64) {
            const int z = tid - 64;        // 0..191 -> rows 33..38
            if (z < 192) sh[33 + (z >> 5)][z & 31] = 0.f;
        }
        if (tid < 64) sh[39 + (tid >> 5)][tid & 31] = 0.f;  // rows 39,40
        for (int idx = tid; idx < 32 * 16; idx += 256) {
            const int row = idx >> 4, c4 = (idx & 15) << 2;
            const int n = t0 + row;
            f4 v = {0.f, 0.f, 0.f, 0.f};
            if (n < N1) v = *(const f4*)&feat[(b * N1 + n) * 64 + c4];
            *(f4*)&sx[row][c4] = v;
        }
    }
    __syncthreads();

    // ---- emission rows r = w, w+4, ..., w+28 per wave (8 rows/wave) ----
    const float bias_l = (lane < C1) ? sb[lane] : 0.f;
    for (int r = w; r < 32; r += 4) {
        const int n = t0 + r;
        float val;
        if (n < N1) {
            const float xl = sx[r][lane];
            float z = 0.f, wv = 0.f;
            for (int dd = 0; dd < 64; ++dd) {
                const float xd = sx[r][dd];            // broadcast
                z  += sP[dd][lane] * xd;               // conflict-free banks
                wv += sW[dd][lane & 31] * xd;
            }
            float xz = xl * z;
            for (int m2 = 32; m2 >= 1; m2 >>= 1) xz += __shfl_xor(xz, m2);
            val = (lane < C1) ? (bias_l + wv - 0.5f * xz) : BIG_NEG;
        } else if (n == N1) {
            val = (lane == C1) ? 0.0f : BIG_NEG;       // EOS row
        } else {
            val = 0.0f;                                // zero padding
        }
        if (lane < 32) sh[r + 1][lane] = val;
    }
    __syncthreads();

    // ---- prefix scan over 40 rows: 8 groups x 5 serial + shfl_up over 8 ----
    {
        const int sc = tid >> 3;   // column 0..31
        const int g  = tid & 7;    // group 0..7
        float p0 = sh[5 * g + 1][sc];
        float p1 = p0 + sh[5 * g + 2][sc];
        float p2 = p1 + sh[5 * g + 3][sc];
        float p3 = p2 + sh[5 * g + 4][sc];
        float p4 = p3 + sh[5 * g + 5][sc];
        float sum = p4;
#pragma unroll
        for (int off = 1; off < 8; off <<= 1) {
            float nv = __shfl_up(sum, off, 8);
            if (g >= off) sum += nv;
        }
        const float excl = sum - p4;
        sh[5 * g + 1][sc] = p0 + excl;
        sh[5 * g + 2][sc] = p1 + excl;
        sh[5 * g + 3][sc] = p2 + excl;
        sh[5 * g + 4][sc] = p3 + excl;
        sh[5 * g + 5][sc] = p4 + excl;
    }

    const int cp = tid >> 3;
    const int c0 = (tid & 7) << 2;
    const f4 tr4 = *(const f4*)&ws[WS_TRANS + cp * 32 + c0];
    f4 in4 = {0.f, 0.f, 0.f, 0.f};
    if (t0 == 0) in4 = *(const f4*)&ws[WS_INIT + c0];
    const float emisN = (cp == C1) ? 0.0f : BIG_NEG;
    __syncthreads();

#pragma unroll
    for (int j = 0; j < TT; ++j) {
        const int t = t0 + j;
        if (t >= N1) break;
        f4 base_j = tr4;
        if (t == 0) base_j += in4;
        const f4 Sj = *(const f4*)&sh[j][c0];
        const int keos = N1 - t;  // matches k only when 1 <= keos <= 31
        const size_t obase =
            (size_t)(b * N1 + t) * 32768 + (size_t)(cp * 32 + c0);
#pragma unroll 4
        for (int k = 0; k < K; ++k) {
            const f4 len4 = *(const f4*)&ws[WS_LEN + k * 32 + c0];
            const f4 win = *(const f4*)&sh[j + k][c0] - Sj;
            f4 o = base_j + len4 + win;
            if (k == keos) o += emisN;
            *(f4*)&out[obase + (size_t)k * 1024] = o;
        }
    }
}

// ---------------------------------------------------------------------------
extern "C" void kernel_launch(void* const* d_in, const int* in_sizes, int n_in,
                              void* d_out, int out_size, void* d_ws, size_t ws_size,
                              hipStream_t stream) {
    const float* feat = (const float*)d_in[0];
    const float* tl   = (const float*)d_in[1];
    const float* il   = (const float*)d_in[2];
    const float* plr  = (const float*)d_in[3];
    const float* gm   = (const float*)d_in[4];
    const float* gc   = (const float*)d_in[5];
    float* ws  = (float*)d_ws;
    float* out = (float*)d_out;

    hipLaunchKernelGGL(k_prep, dim3(1), dim3(512), 0, stream, tl, il, plr, gc, gm, ws);
    hipLaunchKernelGGL(k_main, dim3(B * 256), dim3(256), 0, stream, feat, ws, out);
}

// Round 15
// 83.448 us; speedup vs baseline: 1.0833x; 1.0833x over previous
//
#include <hip/hip_runtime.h>
#include <math.h>

#define BIG_NEG -1.0e9f

typedef float f4 __attribute__((ext_vector_type(4)));

// Problem constants (fixed by setup_inputs)
constexpr int B  = 4;
constexpr int N1 = 511;
constexpr int C1 = 31;
constexpr int K  = 32;
constexpr int N  = N1 + 1;        // 512
constexpr int C  = C1 + 1;        // 32

// Workspace layout (float offsets)
constexpr int WS_TRANS = 0;                    // [32][32]
constexpr int WS_INIT  = 1024;                 // [32]
constexpr int WS_LEN   = 1056;                 // [32][32]  (K x C)
constexpr int WS_EMIS  = 8256;                 // [B][N][C] = 65536 (offset kept)

// ---------------------------------------------------------------------------
// k_pe: 511 blocks x 256 threads. EACH block redundantly runs the rank-4
// frozen-pivot GJ (verified R9 math, re-partitioned to 8 chunks/thread),
// computes W/bias into LDS, then one emission row per wave (4 rows/block).
// Block 0 additionally writes the small tables. All blocks concurrent
// (54 KB LDS -> 2 blocks/CU; 511 <= 512 slots) => GJ cost is ~5 us wall.
// ---------------------------------------------------------------------------
__global__ __launch_bounds__(256) void k_pe(const float* __restrict__ feat,
                                            const float* __restrict__ tl,
                                            const float* __restrict__ il,
                                            const float* __restrict__ plr,
                                            const float* __restrict__ cov,
                                            const float* __restrict__ means,
                                            float* __restrict__ ws) {
    __shared__ float M[64][132];    // [cov | I]; left half later holds P
    __shared__ float cP[2][4][64];  // published pivot cols (dbuf)
    __shared__ float Bsave[16][16]; // pivot blocks
    __shared__ float mu[C1][64];
    __shared__ float sW[64][32];    // wT[dd][c]
    __shared__ float sb[32];        // bias
    __shared__ float xs[4][64];     // per-wave x

    const int tid = threadIdx.x;
    const int bid = blockIdx.x;
    const int ii = tid >> 2;       // row 0..63
    const int cg = tid & 3;        // owns f4 chunks {cg, cg+4, ..., cg+28}
    f4* Mrow = (f4*)&M[ii][0];

    // ---- block 0: small tables (global writes, independent of LDS) ----
    if (bid == 0) {
        for (int idx = tid; idx < 1024; idx += 256) {
            const int i = idx >> 5, j = idx & 31;
            float lv;
            if (j < C1) {
                float lr = plr[j];
                lv = (float)i * lr - expf(lr) - lgammaf((float)i + 1.0f);
            } else {
                lv = (i == 1) ? 0.0f : BIG_NEG;
            }
            ws[WS_LEN + idx] = lv;
            if (i == C1) ws[WS_TRANS + idx] = 0.0f;
            else if (j == C1) ws[WS_TRANS + idx] = BIG_NEG;
        }
        if (tid < B * C) {   // EOS emission rows
            const int bb = tid >> 5, cc = tid & 31;
            ws[WS_EMIS + (bb * N + N1) * C + cc] = (cc == C1) ? 0.0f : BIG_NEG;
        }
        if (tid < C1) {      // trans log_softmax over axis 0, masked diagonal
            const int jj = tid;
            float m = BIG_NEG;
            for (int r = 0; r < C1; ++r) {
                float v = (r == jj) ? BIG_NEG : tl[r * C1 + jj];
                m = fmaxf(m, v);
            }
            float s = 0.0f;
            for (int r = 0; r < C1; ++r) {
                float v = (r == jj) ? BIG_NEG : tl[r * C1 + jj];
                s += expf(v - m);
            }
            float lse = m + logf(s);
            for (int r = 0; r < C1; ++r) {
                float v = (r == jj) ? BIG_NEG : tl[r * C1 + jj];
                ws[WS_TRANS + r * 32 + jj] = v - lse;
            }
        }
        if (tid == 32) {     // init_a
            float m = -1.0e30f;
            for (int cc = 0; cc < C1; ++cc) m = fmaxf(m, il[cc]);
            float s = 0.0f;
            for (int cc = 0; cc < C1; ++cc) s += expf(il[cc] - m);
            float lse = m + logf(s);
            for (int cc = 0; cc < C1; ++cc) ws[WS_INIT + cc] = il[cc] - lse;
            ws[WS_INIT + C1] = BIG_NEG;
        }
    }

    // ---- load [cov | I] (8 chunks/thread) ----
#pragma unroll
    for (int h = 0; h < 8; ++h) {
        const int q = cg + 4 * h;
        if (q < 16) {
            Mrow[q] = *(const f4*)&cov[ii * 64 + 4 * q];
        } else {
            const int r0 = 4 * (q - 16);
            f4 e = {(ii == r0) ? 1.f : 0.f, (ii == r0 + 1) ? 1.f : 0.f,
                    (ii == r0 + 2) ? 1.f : 0.f, (ii == r0 + 3) ? 1.f : 0.f};
            Mrow[q] = e;
        }
    }
    if (cg == 0) {
        cP[0][0][ii] = cov[ii * 64 + 0];
        cP[0][1][ii] = cov[ii * 64 + 1];
        cP[0][2][ii] = cov[ii * 64 + 2];
        cP[0][3][ii] = cov[ii * 64 + 3];
    }
    for (int idx = tid; idx < C1 * 64; idx += 256)
        mu[idx >> 6][idx & 63] = means[idx];
    __syncthreads();

    // ---- rank-4 block GJ: 16 steps, ONE barrier each, frozen pivot rows ----
    float detprod = 1.0f;
    for (int st = 0; st < 16; ++st) {
        const int s = st << 2;
        const int par = st & 1;
        const float T00 = cP[par][0][s + 0], T01 = cP[par][0][s + 1],
                    T02 = cP[par][0][s + 2], T03 = cP[par][0][s + 3];
        const float T10 = cP[par][1][s + 0], T11 = cP[par][1][s + 1],
                    T12 = cP[par][1][s + 2], T13 = cP[par][1][s + 3];
        const float T20 = cP[par][2][s + 0], T21 = cP[par][2][s + 1],
                    T22 = cP[par][2][s + 2], T23 = cP[par][2][s + 3];
        const float T30 = cP[par][3][s + 0], T31 = cP[par][3][s + 1],
                    T32 = cP[par][3][s + 2], T33 = cP[par][3][s + 3];
        const float r0 = __builtin_amdgcn_rcpf(T00);
        const float l10 = T10 * r0, l20 = T20 * r0, l30 = T30 * r0;
        const float u11 = T11 - l10 * T01, u12 = T12 - l10 * T02,
                    u13 = T13 - l10 * T03;
        const float r1 = __builtin_amdgcn_rcpf(u11);
        const float l21 = (T21 - l20 * T01) * r1;
        const float l31 = (T31 - l30 * T01) * r1;
        const float u22 = T22 - l20 * T02 - l21 * u12;
        const float u23 = T23 - l20 * T03 - l21 * u13;
        const float u32 = T32 - l30 * T02 - l31 * u12;
        const float u33t = T33 - l30 * T03 - l31 * u13;
        const float r2 = __builtin_amdgcn_rcpf(u22);
        const float l32 = u32 * r2;
        const float u33 = u33t - l32 * u23;
        const float r3 = __builtin_amdgcn_rcpf(u33);
        detprod *= T00 * u11 * u22 * u33;

        if (tid < 16) Bsave[st][tid] = cP[par][tid & 3][s + (tid >> 2)];

        const float m0 = cP[par][0][ii], m1 = cP[par][1][ii],
                    m2 = cP[par][2][ii], m3 = cP[par][3][ii];
        const float y0 = m0;
        const float y1 = m1 - l10 * y0;
        const float y2 = m2 - l20 * y0 - l21 * y1;
        const float y3 = m3 - l30 * y0 - l31 * y1 - l32 * y2;
        float g3 = y3 * r3;
        float g2 = (y2 - u23 * g3) * r2;
        float g1 = (y1 - u12 * g2 - u13 * g3) * r1;
        float g0 = (y0 - T01 * g1 - T02 * g2 - T03 * g3) * r0;
        const bool pivrow = (unsigned)(ii - s) < 4u;
        if (pivrow) { g0 = 0.f; g1 = 0.f; g2 = 0.f; g3 = 0.f; }

        const f4* Ms0 = (const f4*)&M[s + 0][0];
        const f4* Ms1 = (const f4*)&M[s + 1][0];
        const f4* Ms2 = (const f4*)&M[s + 2][0];
        const f4* Ms3 = (const f4*)&M[s + 3][0];
        const int qpub = st + 1;   // chunk holding cols s+4..s+7
#pragma unroll
        for (int h = 0; h < 8; ++h) {
            const int q = cg + 4 * h;
            const int k0 = 4 * q;
            const bool active = (k0 < 64) ? (k0 + 3 >= s) : (k0 - 64 <= s + 3);
            if (!active) continue;
            f4 v = Mrow[q] - g0 * Ms0[q] - g1 * Ms1[q]
                           - g2 * Ms2[q] - g3 * Ms3[q];
            if (!pivrow) Mrow[q] = v;      // pivot rows frozen (no race)
            if (st < 15 && q == qpub) {
                cP[par ^ 1][0][ii] = v.x;
                cP[par ^ 1][1][ii] = v.y;
                cP[par ^ 1][2][ii] = v.z;
                cP[par ^ 1][3][ii] = v.w;
            }
        }
        __syncthreads();
    }

    // ---- extraction: P row ii -> stash into LEFT half of M ----
    {
        const int kb = ii >> 2, rsel = ii & 3, base = kb << 2;
        const float* Bk = &Bsave[kb][0];
        const float T00 = Bk[0],  T01 = Bk[4],  T02 = Bk[8],  T03 = Bk[12];
        const float T10 = Bk[1],  T11 = Bk[5],  T12 = Bk[9],  T13 = Bk[13];
        const float T20 = Bk[2],  T21 = Bk[6],  T22 = Bk[10], T23 = Bk[14];
        const float T30 = Bk[3],  T31 = Bk[7],  T32 = Bk[11], T33 = Bk[15];
        const float r0 = __builtin_amdgcn_rcpf(T00);
        const float l10 = T10 * r0, l20 = T20 * r0, l30 = T30 * r0;
        const float u11 = T11 - l10 * T01, u12 = T12 - l10 * T02,
                    u13 = T13 - l10 * T03;
        const float r1 = __builtin_amdgcn_rcpf(u11);
        const float l21 = (T21 - l20 * T01) * r1;
        const float l31 = (T31 - l30 * T01) * r1;
        const float u22 = T22 - l20 * T02 - l21 * u12;
        const float u23 = T23 - l20 * T03 - l21 * u13;
        const float u32 = T32 - l30 * T02 - l31 * u12;
        const float u33t = T33 - l30 * T03 - l31 * u13;
        const float r2 = __builtin_amdgcn_rcpf(u22);
        const float l32 = u32 * r2;
        const float u33 = u33t - l32 * u23;
        const float r3 = __builtin_amdgcn_rcpf(u33);
        const float m0 = (rsel == 0) ? 1.f : 0.f;
        const float m1 = (rsel == 1) ? 1.f : 0.f;
        const float m2 = (rsel == 2) ? 1.f : 0.f;
        const float m3 = (rsel == 3) ? 1.f : 0.f;
        const float y0 = m0;
        const float y1 = m1 - l10 * y0;
        const float y2 = m2 - l20 * y0 - l21 * y1;
        const float y3 = m3 - l30 * y0 - l31 * y1 - l32 * y2;
        const float x3 = y3 * r3;
        const float x2 = (y2 - u23 * x3) * r2;
        const float x1 = (y1 - u12 * x2 - u13 * x3) * r1;
        const float x0 = (y0 - T01 * x1 - T02 * x2 - T03 * x3) * r0;

        const f4* R0 = (const f4*)&M[base + 0][64];
        const f4* R1 = (const f4*)&M[base + 1][64];
        const f4* R2 = (const f4*)&M[base + 2][64];
        const f4* R3 = (const f4*)&M[base + 3][64];
#pragma unroll
        for (int h = 0; h < 4; ++h) {
            const int j = cg + 4 * h;          // right-half chunk 0..15
            f4 v = x0 * R0[j] + x1 * R1[j] + x2 * R2[j] + x3 * R3[j];
            *(f4*)&M[ii][4 * j] = v;           // left half <- P (no global)
        }
    }
    __syncthreads();

    // ---- sW[dd][c] = P[dd][:] . mu_c ; bias via 8-lane shfl ----
    {
        const int c = tid >> 3;    // 0..31
        const int l = tid & 7;
        if (c < C1) {
            const f4* muc = (const f4*)&mu[c][0];
            float qacc = 0.0f;
#pragma unroll
            for (int h = 0; h < 8; ++h) {
                const int dd = l + 8 * h;
                const f4* Mr = (const f4*)&M[dd][0];
                f4 a4 = {0.f, 0.f, 0.f, 0.f};
#pragma unroll
                for (int e4 = 0; e4 < 16; ++e4) a4 += Mr[e4] * muc[e4];
                float a = (a4.x + a4.y) + (a4.z + a4.w);
                sW[dd][c] = a;
                qacc += a * mu[c][dd];
            }
            for (int m2 = 4; m2 >= 1; m2 >>= 1)
                qacc += __shfl_xor(qacc, m2, 8);
            if (l == 0)
                sb[c] = -0.5f * (64.0f * 1.8378770664093453f +
                                 logf(detprod) + qacc);
        }
    }
    __syncthreads();

    // ---- emission: one row per wave (flat = bid*4 + w, 0..2043) ----
    {
        const int w = tid >> 6, lane = tid & 63;
        const int flat = bid * 4 + w;
        const int b = flat / N1, n = flat - b * N1;
        const float x = feat[flat * 64 + lane];
        xs[w][lane] = x;   // wave-local; lgkmcnt ordering suffices

        float z = 0.0f;
        for (int dd = 0; dd < 64; ++dd) z += M[dd][lane] * xs[w][dd];

        float xz = x * z;
        for (int m2 = 32; m2 >= 1; m2 >>= 1) xz += __shfl_xor(xz, m2);

        float val = BIG_NEG;
        if (lane < C1) {
            float s = sb[lane] - 0.5f * xz;
            for (int dd = 0; dd < 64; ++dd) s += sW[dd][lane] * xs[w][dd];
            val = s;
        }
        if (lane < C) ws[WS_EMIS + (b * N + n) * C + lane] = val;
    }
}

// ---------------------------------------------------------------------------
// Main assembly [R12 verbatim]: one block per (b, 2-t tile); grid 1024.
// LEN staged in LDS; plain coalesced f4 stores.
// ---------------------------------------------------------------------------
__global__ __launch_bounds__(256) void k_main(const float* __restrict__ ws,
                                              float* __restrict__ out) {
    constexpr int TT = 2;
    const int bid = blockIdx.x;
    const int b = bid >> 8;
    const int t0 = (bid & 255) << 1;
    const int tid = threadIdx.x;

    __shared__ __align__(16) float slen[K * C];  // 4 KB
    __shared__ float sh[41][36];                 // S[0..40] per column

    for (int idx = tid; idx < K * C / 4; idx += 256)
        *(f4*)&slen[4 * idx] = *(const f4*)&ws[WS_LEN + 4 * idx];

    for (int idx = tid; idx < 33 * 8; idx += 256) {
        const int r = idx >> 3, c4 = (idx & 7) << 2;
        const int n = t0 + r;
        f4 v = {0.f, 0.f, 0.f, 0.f};
        if (n < N) v = *(const f4*)&ws[WS_EMIS + (b * N + n) * C + c4];
        *(f4*)&sh[r + 1][c4] = v;
    }
    if (tid < 32) sh[0][tid] = 0.f;
    if (tid >= 64 && tid < 288 - 32) {   // zero rows 34..39
        const int z = tid - 64;
        sh[34 + (z >> 5)][z & 31] = 0.f;
    }
    if (tid >= 224 && tid < 256) sh[40][tid - 224] = 0.f;
    __syncthreads();

    // prefix scan over 40 rows: 8 groups x 5 serial + shfl_up over 8 groups
    {
        const int sc = tid >> 3;   // column 0..31
        const int g  = tid & 7;    // group 0..7
        float p0 = sh[5 * g + 1][sc];
        float p1 = p0 + sh[5 * g + 2][sc];
        float p2 = p1 + sh[5 * g + 3][sc];
        float p3 = p2 + sh[5 * g + 4][sc];
        float p4 = p3 + sh[5 * g + 5][sc];
        float sum = p4;
#pragma unroll
        for (int off = 1; off < 8; off <<= 1) {
            float nv = __shfl_up(sum, off, 8);
            if (g >= off) sum += nv;
        }
        const float excl = sum - p4;
        sh[5 * g + 1][sc] = p0 + excl;
        sh[5 * g + 2][sc] = p1 + excl;
        sh[5 * g + 3][sc] = p2 + excl;
        sh[5 * g + 4][sc] = p3 + excl;
        sh[5 * g + 5][sc] = p4 + excl;
    }

    const int cp = tid >> 3;
    const int c0 = (tid & 7) << 2;
    const f4 tr4 = *(const f4*)&ws[WS_TRANS + cp * 32 + c0];
    f4 in4 = {0.f, 0.f, 0.f, 0.f};
    if (t0 == 0) in4 = *(const f4*)&ws[WS_INIT + c0];
    const float emisN = (cp == C1) ? 0.0f : BIG_NEG;
    __syncthreads();

#pragma unroll
    for (int j = 0; j < TT; ++j) {
        const int t = t0 + j;
        if (t >= N1) break;
        f4 base_j = tr4;
        if (t == 0) base_j += in4;
        const f4 Sj = *(const f4*)&sh[j][c0];
        const int keos = N1 - t;  // matches k only when 1 <= keos <= 31
        const size_t obase =
            (size_t)(b * N1 + t) * 32768 + (size_t)(cp * 32 + c0);
#pragma unroll 4
        for (int k = 0; k < K; ++k) {
            const f4 len4 = *(const f4*)&slen[k * 32 + c0];
            const f4 win = *(const f4*)&sh[j + k][c0] - Sj;
            f4 o = base_j + len4 + win;
            if (k == keos) o += emisN;
            *(f4*)&out[obase + (size_t)k * 1024] = o;
        }
    }
}

// ---------------------------------------------------------------------------
extern "C" void kernel_launch(void* const* d_in, const int* in_sizes, int n_in,
                              void* d_out, int out_size, void* d_ws, size_t ws_size,
                              hipStream_t stream) {
    const float* feat = (const float*)d_in[0];
    const float* tl   = (const float*)d_in[1];
    const float* il   = (const float*)d_in[2];
    const float* plr  = (const float*)d_in[3];
    const float* gm   = (const float*)d_in[4];
    const float* gc   = (const float*)d_in[5];
    float* ws  = (float*)d_ws;
    float* out = (float*)d_out;

    hipLaunchKernelGGL(k_pe, dim3(B * N1 / 4), dim3(256), 0, stream,
                       feat, tl, il, plr, gc, gm, ws);
    hipLaunchKernelGGL(k_main, dim3(B * 256), dim3(256), 0, stream, ws, out);
}

// Round 16
// 79.474 us; speedup vs baseline: 1.1374x; 1.0500x over previous
//
#include <hip/hip_runtime.h>
#include <math.h>

#define BIG_NEG -1.0e9f

typedef float f4 __attribute__((ext_vector_type(4)));

// Problem constants (fixed by setup_inputs)
constexpr int B  = 4;
constexpr int N1 = 511;
constexpr int C1 = 31;
constexpr int K  = 32;
constexpr int N  = N1 + 1;        // 512
constexpr int C  = C1 + 1;        // 32

// Workspace layout (float offsets)
constexpr int WS_TRANS = 0;                    // [32][32]
constexpr int WS_INIT  = 1024;                 // [32]
constexpr int WS_LEN   = 1056;                 // [32][32]  (K x C)
constexpr int WS_P     = 2080;                 // [64][64]  precision matrix
constexpr int WS_W     = 6176;                 // [64][32]  wT[dd][c]
constexpr int WS_BIAS  = 8224;                 // [32]
constexpr int WS_EMIS  = 8256;                 // [B][N][C] = 65536

// ---------------------------------------------------------------------------
// k_prep: PURE rank-4 frozen-pivot-row block Gauss-Jordan (16 barriers) +
// extraction + wT + bias. Tables moved to k_emis (no GJ dependency).
// [GJ math verified R9/R12 — unchanged]
// ---------------------------------------------------------------------------
__global__ __launch_bounds__(512) void k_prep(const float* __restrict__ cov,
                                              const float* __restrict__ means,
                                              float* __restrict__ ws) {
    __shared__ float M[64][132];    // [cov | I], row stride 132 (16B aligned)
    __shared__ float cP[2][4][64];  // published pivot cols s..s+3 (dbuf)
    __shared__ float Bsave[16][16]; // B_k blocks, row-major
    __shared__ float mu[C1][64];

    const int tid = threadIdx.x;
    const int ii = tid >> 3;       // row 0..63
    const int cg = tid & 7;        // owns f4 chunks {cg, cg+8, cg+16, cg+24}

    f4* Mrow = (f4*)&M[ii][0];

    // ---- load [cov | I] ----
    {
        Mrow[cg]     = *(const f4*)&cov[ii * 64 + 4 * cg];
        Mrow[cg + 8] = *(const f4*)&cov[ii * 64 + 4 * (cg + 8)];
        const int r0 = 4 * cg, r1 = 4 * (cg + 8);
        f4 e1 = {(ii == r0) ? 1.f : 0.f, (ii == r0 + 1) ? 1.f : 0.f,
                 (ii == r0 + 2) ? 1.f : 0.f, (ii == r0 + 3) ? 1.f : 0.f};
        f4 e2 = {(ii == r1) ? 1.f : 0.f, (ii == r1 + 1) ? 1.f : 0.f,
                 (ii == r1 + 2) ? 1.f : 0.f, (ii == r1 + 3) ? 1.f : 0.f};
        Mrow[cg + 16] = e1;
        Mrow[cg + 24] = e2;
    }
    if (cg == 0) {
        cP[0][0][ii] = cov[ii * 64 + 0];
        cP[0][1][ii] = cov[ii * 64 + 1];
        cP[0][2][ii] = cov[ii * 64 + 2];
        cP[0][3][ii] = cov[ii * 64 + 3];
    }
    for (int idx = tid; idx < C1 * 64; idx += 512)
        mu[idx >> 6][idx & 63] = means[idx];
    __syncthreads();

    // ---- rank-4 block GJ: 16 steps, ONE barrier each, pivot rows frozen ----
    float detprod = 1.0f;
    for (int st = 0; st < 16; ++st) {
        const int s = st << 2;
        const int par = st & 1;
        const float T00 = cP[par][0][s + 0], T01 = cP[par][0][s + 1],
                    T02 = cP[par][0][s + 2], T03 = cP[par][0][s + 3];
        const float T10 = cP[par][1][s + 0], T11 = cP[par][1][s + 1],
                    T12 = cP[par][1][s + 2], T13 = cP[par][1][s + 3];
        const float T20 = cP[par][2][s + 0], T21 = cP[par][2][s + 1],
                    T22 = cP[par][2][s + 2], T23 = cP[par][2][s + 3];
        const float T30 = cP[par][3][s + 0], T31 = cP[par][3][s + 1],
                    T32 = cP[par][3][s + 2], T33 = cP[par][3][s + 3];
        const float r0 = __builtin_amdgcn_rcpf(T00);
        const float l10 = T10 * r0, l20 = T20 * r0, l30 = T30 * r0;
        const float u11 = T11 - l10 * T01, u12 = T12 - l10 * T02,
                    u13 = T13 - l10 * T03;
        const float r1 = __builtin_amdgcn_rcpf(u11);
        const float l21 = (T21 - l20 * T01) * r1;
        const float l31 = (T31 - l30 * T01) * r1;
        const float u22 = T22 - l20 * T02 - l21 * u12;
        const float u23 = T23 - l20 * T03 - l21 * u13;
        const float u32 = T32 - l30 * T02 - l31 * u12;
        const float u33t = T33 - l30 * T03 - l31 * u13;
        const float r2 = __builtin_amdgcn_rcpf(u22);
        const float l32 = u32 * r2;
        const float u33 = u33t - l32 * u23;
        const float r3 = __builtin_amdgcn_rcpf(u33);
        detprod *= T00 * u11 * u22 * u33;

        if (tid < 16) Bsave[st][tid] = cP[par][tid & 3][s + (tid >> 2)];

        const float m0 = cP[par][0][ii], m1 = cP[par][1][ii],
                    m2 = cP[par][2][ii], m3 = cP[par][3][ii];
        const float y0 = m0;
        const float y1 = m1 - l10 * y0;
        const float y2 = m2 - l20 * y0 - l21 * y1;
        const float y3 = m3 - l30 * y0 - l31 * y1 - l32 * y2;
        float g3 = y3 * r3;
        float g2 = (y2 - u23 * g3) * r2;
        float g1 = (y1 - u12 * g2 - u13 * g3) * r1;
        float g0 = (y0 - T01 * g1 - T02 * g2 - T03 * g3) * r0;
        const bool pivrow = (unsigned)(ii - s) < 4u;
        if (pivrow) { g0 = 0.f; g1 = 0.f; g2 = 0.f; g3 = 0.f; }

        const f4* Ms0 = (const f4*)&M[s + 0][0];
        const f4* Ms1 = (const f4*)&M[s + 1][0];
        const f4* Ms2 = (const f4*)&M[s + 2][0];
        const f4* Ms3 = (const f4*)&M[s + 3][0];
        const int qpub = st + 1;   // chunk holding cols s+4..s+7
#pragma unroll
        for (int h = 0; h < 4; ++h) {
            const int q = cg + 8 * h;
            const int k0 = 4 * q;
            const bool active = (k0 < 64) ? (k0 + 3 >= s) : (k0 - 64 <= s + 3);
            if (!active) continue;
            f4 v = Mrow[q] - g0 * Ms0[q] - g1 * Ms1[q]
                           - g2 * Ms2[q] - g3 * Ms3[q];
            if (!pivrow) Mrow[q] = v;      // pivot rows frozen (no race)
            if (st < 15 && q == qpub) {
                cP[par ^ 1][0][ii] = v.x;
                cP[par ^ 1][1][ii] = v.y;
                cP[par ^ 1][2][ii] = v.z;
                cP[par ^ 1][3][ii] = v.w;
            }
        }
        __syncthreads();
    }

    // ---- extraction: P[ii][:] = (invB_k row (ii&3)) . Mright[4k..4k+3][:] ----
    {
        const int kb = ii >> 2, rsel = ii & 3, base = kb << 2;
        const float* Bk = &Bsave[kb][0];
        const float T00 = Bk[0],  T01 = Bk[4],  T02 = Bk[8],  T03 = Bk[12];
        const float T10 = Bk[1],  T11 = Bk[5],  T12 = Bk[9],  T13 = Bk[13];
        const float T20 = Bk[2],  T21 = Bk[6],  T22 = Bk[10], T23 = Bk[14];
        const float T30 = Bk[3],  T31 = Bk[7],  T32 = Bk[11], T33 = Bk[15];
        const float r0 = __builtin_amdgcn_rcpf(T00);
        const float l10 = T10 * r0, l20 = T20 * r0, l30 = T30 * r0;
        const float u11 = T11 - l10 * T01, u12 = T12 - l10 * T02,
                    u13 = T13 - l10 * T03;
        const float r1 = __builtin_amdgcn_rcpf(u11);
        const float l21 = (T21 - l20 * T01) * r1;
        const float l31 = (T31 - l30 * T01) * r1;
        const float u22 = T22 - l20 * T02 - l21 * u12;
        const float u23 = T23 - l20 * T03 - l21 * u13;
        const float u32 = T32 - l30 * T02 - l31 * u12;
        const float u33t = T33 - l30 * T03 - l31 * u13;
        const float r2 = __builtin_amdgcn_rcpf(u22);
        const float l32 = u32 * r2;
        const float u33 = u33t - l32 * u23;
        const float r3 = __builtin_amdgcn_rcpf(u33);
        const float m0 = (rsel == 0) ? 1.f : 0.f;
        const float m1 = (rsel == 1) ? 1.f : 0.f;
        const float m2 = (rsel == 2) ? 1.f : 0.f;
        const float m3 = (rsel == 3) ? 1.f : 0.f;
        const float y0 = m0;
        const float y1 = m1 - l10 * y0;
        const float y2 = m2 - l20 * y0 - l21 * y1;
        const float y3 = m3 - l30 * y0 - l31 * y1 - l32 * y2;
        const float x3 = y3 * r3;
        const float x2 = (y2 - u23 * x3) * r2;
        const float x1 = (y1 - u12 * x2 - u13 * x3) * r1;
        const float x0 = (y0 - T01 * x1 - T02 * x2 - T03 * x3) * r0;

        const f4* R0 = (const f4*)&M[base + 0][64];
        const f4* R1 = (const f4*)&M[base + 1][64];
        const f4* R2 = (const f4*)&M[base + 2][64];
        const f4* R3 = (const f4*)&M[base + 3][64];
        f4 va = x0 * R0[cg] + x1 * R1[cg] + x2 * R2[cg] + x3 * R3[cg];
        f4 vb = x0 * R0[cg + 8] + x1 * R1[cg + 8] +
                x2 * R2[cg + 8] + x3 * R3[cg + 8];
        *(f4*)&ws[WS_P + ii * 64 + 4 * cg] = va;
        *(f4*)&ws[WS_P + ii * 64 + 32 + 4 * cg] = vb;
        *(f4*)&M[ii][4 * cg] = va;          // stash P in left half for wT
        *(f4*)&M[ii][32 + 4 * cg] = vb;
    }
    __syncthreads();

    // ---- wT[dd][c] = P[dd][:] . mu_c ; bias via shfl ----
    {
        const int c = tid >> 4;    // 0..31
        const int l = tid & 15;
        if (c < C1) {
            const f4* muc = (const f4*)&mu[c][0];
            float qacc = 0.0f;
#pragma unroll
            for (int h = 0; h < 4; ++h) {
                const int dd = l + 16 * h;
                const f4* Mr = (const f4*)&M[dd][0];
                f4 a4 = {0.f, 0.f, 0.f, 0.f};
#pragma unroll
                for (int e4 = 0; e4 < 16; ++e4) a4 += Mr[e4] * muc[e4];
                float a = (a4.x + a4.y) + (a4.z + a4.w);
                ws[WS_W + dd * 32 + c] = a;
                qacc += a * mu[c][dd];
            }
            for (int m2 = 8; m2 >= 1; m2 >>= 1) qacc += __shfl_xor(qacc, m2, 64);
            if (l == 0)
                ws[WS_BIAS + c] = -0.5f * (64.0f * 1.8378770664093453f +
                                           logf(detprod) + qacc);
        }
    }
}

// ---------------------------------------------------------------------------
// k_emis: emission log-probs (verified R12 pattern) + block 0 writes the
// small tables (TRANS/INIT/LEN/EOS — independent of GJ; hidden under the
// other 510 concurrent blocks).
// ---------------------------------------------------------------------------
__global__ __launch_bounds__(256) void k_emis(const float* __restrict__ feat,
                                              const float* __restrict__ tl,
                                              const float* __restrict__ il,
                                              const float* __restrict__ plr,
                                              float* __restrict__ ws) {
    const int tid = threadIdx.x;
    const int bid = blockIdx.x;

    if (bid == 0) {
        // ---- small tables ----
        for (int idx = tid; idx < 1024; idx += 256) {
            const int i = idx >> 5, j = idx & 31;
            float lv;
            if (j < C1) {
                float lr = plr[j];
                lv = (float)i * lr - expf(lr) - lgammaf((float)i + 1.0f);
            } else {
                lv = (i == 1) ? 0.0f : BIG_NEG;
            }
            ws[WS_LEN + idx] = lv;
            if (i == C1) ws[WS_TRANS + idx] = 0.0f;
            else if (j == C1) ws[WS_TRANS + idx] = BIG_NEG;
        }
        if (tid < B * C) {   // EOS emission rows
            const int bb = tid >> 5, cc = tid & 31;
            ws[WS_EMIS + (bb * N + N1) * C + cc] = (cc == C1) ? 0.0f : BIG_NEG;
        }
        if (tid < C1) {      // trans log_softmax over axis 0, masked diagonal
            const int jj = tid;
            float m = BIG_NEG;
            for (int r = 0; r < C1; ++r) {
                float v = (r == jj) ? BIG_NEG : tl[r * C1 + jj];
                m = fmaxf(m, v);
            }
            float s = 0.0f;
            for (int r = 0; r < C1; ++r) {
                float v = (r == jj) ? BIG_NEG : tl[r * C1 + jj];
                s += expf(v - m);
            }
            float lse = m + logf(s);
            for (int r = 0; r < C1; ++r) {
                float v = (r == jj) ? BIG_NEG : tl[r * C1 + jj];
                ws[WS_TRANS + r * 32 + jj] = v - lse;
            }
        }
        if (tid == 32) {     // init_a
            float m = -1.0e30f;
            for (int cc = 0; cc < C1; ++cc) m = fmaxf(m, il[cc]);
            float s = 0.0f;
            for (int cc = 0; cc < C1; ++cc) s += expf(il[cc] - m);
            float lse = m + logf(s);
            for (int cc = 0; cc < C1; ++cc) ws[WS_INIT + cc] = il[cc] - lse;
            ws[WS_INIT + C1] = BIG_NEG;
        }
    }

    // ---- emission: one row per wave ----
    const int w = tid >> 6, lane = tid & 63;
    const int flat = bid * 4 + w;          // == b*N1 + n, 0..2043
    const int b = flat / N1, n = flat % N1;
    __shared__ float xs[4][64];

    const float x = feat[flat * 64 + lane];
    xs[w][lane] = x;   // wave-local slice; lgkmcnt ordering suffices

    const float* __restrict__ P = ws + WS_P;
    float z = 0.0f;
    for (int dd = 0; dd < 64; ++dd) z += P[dd * 64 + lane] * xs[w][dd];

    float xz = x * z;
    for (int m = 32; m >= 1; m >>= 1) xz += __shfl_xor(xz, m);

    float val = BIG_NEG;
    if (lane < C1) {
        float s = ws[WS_BIAS + lane] - 0.5f * xz;
        const float* __restrict__ wT = ws + WS_W;
        for (int dd = 0; dd < 64; ++dd) s += wT[dd * 32 + lane] * xs[w][dd];
        val = s;
    }
    if (lane < C) ws[WS_EMIS + (b * N + n) * C + lane] = val;
}

// ---------------------------------------------------------------------------
// Main assembly [R12 structure, TT=4]: one block per (b, 4-t tile);
// grid = 4*128 = 512 (2 blocks/CU, 8 waves/CU — above the ~3.4-wave write
// saturation point the fill kernels demonstrate). Halves prologue count.
// ---------------------------------------------------------------------------
__global__ __launch_bounds__(256) void k_main(const float* __restrict__ ws,
                                              float* __restrict__ out) {
    constexpr int TT = 4;
    const int bid = blockIdx.x;
    const int b = bid >> 7;
    const int t0 = (bid & 127) << 2;
    const int tid = threadIdx.x;

    __shared__ __align__(16) float slen[K * C];  // 4 KB
    __shared__ float sh[41][36];                 // S[0..40] per column

    // stage LEN into LDS (one-time VMEM, off the inner loop)
    for (int idx = tid; idx < K * C / 4; idx += 256)
        *(f4*)&slen[4 * idx] = *(const f4*)&ws[WS_LEN + 4 * idx];

    // load emis rows t0..t0+33 (34 rows; rows >= N read as 0 via bound)
    for (int idx = tid; idx < 34 * 8; idx += 256) {
        const int r = idx >> 3, c4 = (idx & 7) << 2;
        const int n = t0 + r;
        f4 v = {0.f, 0.f, 0.f, 0.f};
        if (n < N) v = *(const f4*)&ws[WS_EMIS + (b * N + n) * C + c4];
        *(f4*)&sh[r + 1][c4] = v;
    }
    if (tid < 32) sh[0][tid] = 0.f;
    // zero scan rows 35..40 (6 rows x 32 lanes)
    if (tid >= 64 && tid < 64 + 192) {
        const int z = tid - 64;
        sh[35 + (z >> 5)][z & 31] = 0.f;
    }
    __syncthreads();

    // prefix scan over 40 rows: 8 groups x 5 serial + shfl_up over 8 groups
    {
        const int sc = tid >> 3;   // column 0..31
        const int g  = tid & 7;    // group 0..7
        float p0 = sh[5 * g + 1][sc];
        float p1 = p0 + sh[5 * g + 2][sc];
        float p2 = p1 + sh[5 * g + 3][sc];
        float p3 = p2 + sh[5 * g + 4][sc];
        float p4 = p3 + sh[5 * g + 5][sc];
        float sum = p4;
#pragma unroll
        for (int off = 1; off < 8; off <<= 1) {
            float nv = __shfl_up(sum, off, 8);
            if (g >= off) sum += nv;
        }
        const float excl = sum - p4;
        sh[5 * g + 1][sc] = p0 + excl;
        sh[5 * g + 2][sc] = p1 + excl;
        sh[5 * g + 3][sc] = p2 + excl;
        sh[5 * g + 4][sc] = p3 + excl;
        sh[5 * g + 5][sc] = p4 + excl;
    }

    const int cp = tid >> 3;
    const int c0 = (tid & 7) << 2;
    const f4 tr4 = *(const f4*)&ws[WS_TRANS + cp * 32 + c0];
    f4 in4 = {0.f, 0.f, 0.f, 0.f};
    if (t0 == 0) in4 = *(const f4*)&ws[WS_INIT + c0];
    const float emisN = (cp == C1) ? 0.0f : BIG_NEG;
    __syncthreads();

#pragma unroll
    for (int j = 0; j < TT; ++j) {
        const int t = t0 + j;
        if (t >= N1) break;
        f4 base_j = tr4;
        if (t == 0) base_j += in4;
        const f4 Sj = *(const f4*)&sh[j][c0];
        const int keos = N1 - t;  // matches k only when 1 <= keos <= 31
        const size_t obase =
            (size_t)(b * N1 + t) * 32768 + (size_t)(cp * 32 + c0);
#pragma unroll 4
        for (int k = 0; k < K; ++k) {
            const f4 len4 = *(const f4*)&slen[k * 32 + c0];
            const f4 win = *(const f4*)&sh[j + k][c0] - Sj;
            f4 o = base_j + len4 + win;
            if (k == keos) o += emisN;
            *(f4*)&out[obase + (size_t)k * 1024] = o;
        }
    }
}

// ---------------------------------------------------------------------------
extern "C" void kernel_launch(void* const* d_in, const int* in_sizes, int n_in,
                              void* d_out, int out_size, void* d_ws, size_t ws_size,
                              hipStream_t stream) {
    const float* feat = (const float*)d_in[0];
    const float* tl   = (const float*)d_in[1];
    const float* il   = (const float*)d_in[2];
    const float* plr  = (const float*)d_in[3];
    const float* gm   = (const float*)d_in[4];
    const float* gc   = (const float*)d_in[5];
    float* ws  = (float*)d_ws;
    float* out = (float*)d_out;

    hipLaunchKernelGGL(k_prep, dim3(1), dim3(512), 0, stream, gc, gm, ws);
    hipLaunchKernelGGL(k_emis, dim3(B * N1 / 4), dim3(256), 0, stream,
                       feat, tl, il, plr, ws);
    hipLaunchKernelGGL(k_main, dim3(B * 128), dim3(256), 0, stream, ws, out);
}